// Round 1
// baseline (429.382 us; speedup 1.0000x reference)
//
#include <hip/hip_runtime.h>
#include <stdint.h>

typedef __bf16 bf16x8 __attribute__((ext_vector_type(8)));
typedef float  f32x4  __attribute__((ext_vector_type(4)));
typedef float  f32x16 __attribute__((ext_vector_type(16)));
typedef unsigned short u16;

// ---- workspace layout (bytes) ----
#define WCT_OFF   0u          // 144*256 bf16 = 73728   (W^T, fused Wq|Wk|Wv)
#define SC_OFF    73728u      // 144 f32 BN scale
#define SH_OFF    74304u      // 144 f32 BN shift
#define BST_OFF   75008u      // 23 * 12288 bf16 = 565248 (banded conv B, frag-lane order)
#define MSUM_OFF  640256u     // 16*16*2 f32 (softmax max, 1/sum)
#define LCB_OFF   642304u     // 16*16*64 f32 (Lc + pos_b)
#define QP_OFF    707840u     // 16*4096*64 bf16 (q, BN'd, [b][pos][ch])
#define KT_OFF    9096448u    // 16*16*4096 bf16 (k, [b][ch][pos])
#define VT_OFF    11193600u   // 16*64*4096 bf16 (v, BN'd, [b][ch][pos] = per-v image)
#define LP_OFF    19582208u   // Lp bf16 [bchunk][pos][v*16+k], 8388608 B per b
#define LP_PER_B  8388608u

// ------------------------------------------------------------------
// Kernel P: precompute WcT (bf16), BN affine, banded conv B matrices
// ------------------------------------------------------------------
__global__ void kP(const float* Wq, const float* Wk, const float* Wv,
                   const float* gq, const float* bq, const float* mq, const float* vq,
                   const float* gv, const float* bv, const float* mv, const float* vvar,
                   const float* pw, char* ws) {
  int t = threadIdx.x;
  if (blockIdx.x == 0) {
    __bf16* wct = (__bf16*)(ws + WCT_OFF);
    for (int i = 0; i < 144; ++i) {
      int n = i, c = t;
      float val;
      if (n < 64)      val = Wq[c * 64 + n];
      else if (n < 80) val = Wk[c * 16 + (n - 64)];
      else             val = Wv[c * 64 + (n - 80)];
      wct[n * 256 + c] = (__bf16)val;
    }
    if (t < 144) {
      float s, sh;
      if (t < 64)      { s = gq[t] * rsqrtf(vq[t] + 1e-3f); sh = bq[t] - mq[t] * s; }
      else if (t < 80) { s = 1.f; sh = 0.f; }
      else { int i = t - 80; s = gv[i] * rsqrtf(vvar[i] + 1e-3f); sh = bv[i] - mv[i] * s; }
      ((float*)(ws + SC_OFF))[t] = s;
      ((float*)(ws + SH_OFF))[t] = sh;
    }
  } else {
    int dy = blockIdx.x - 1;               // 0..22
    __bf16* bst = (__bf16*)(ws + BST_OFF) + dy * 12288;
    for (int i = 0; i < 48; ++i) {
      int idx = i * 256 + t;               // < 12288
      int nt = idx / 1536, r1 = idx % 1536;
      int ks = r1 / 512,   r2 = r1 % 512;
      int l = r2 >> 3, e = r2 & 7;
      int j = ks * 16 + (l >> 5) * 8 + e;  // K index 0..47
      int n = nt * 32 + (l & 31);          // N index 0..255
      int xr = n >> 4, kch = n & 15;
      int dxw = j - xr - 5;                // img col = x + dxw - 11
      float val = (dxw >= 0 && dxw < 23) ? pw[(dy * 23 + dxw) * 16 + kch] : 0.f;
      bst[idx] = (__bf16)val;
    }
  }
}

// ------------------------------------------------------------------
// Kernel A: fused q/k/v projections (M=65536,K=256,N=144) + BN, MFMA 16x16x32
// ------------------------------------------------------------------
__global__ __launch_bounds__(256) void kA(const float* x, char* ws) {
  int t = threadIdx.x, w = t >> 6, l = t & 63;
  int m0 = blockIdx.x * 256;
  int b = m0 >> 12;
  int posb = m0 & 4095;
  const __bf16* wct = (const __bf16*)(ws + WCT_OFF);
  const float* sc = (const float*)(ws + SC_OFF);
  const float* sh = (const float*)(ws + SH_OFF);
  __bf16* qp = (__bf16*)(ws + QP_OFF);
  __bf16* kt = (__bf16*)(ws + KT_OFF);
  __bf16* vt = (__bf16*)(ws + VT_OFF);

  int rl = l & 15;      // A row / B col / C col within frag
  int kg = l >> 4;      // k-group 0..3

  f32x4 acc[4][9];
#pragma unroll
  for (int mf = 0; mf < 4; ++mf)
#pragma unroll
    for (int nf = 0; nf < 9; ++nf)
#pragma unroll
      for (int q = 0; q < 4; ++q) acc[mf][nf][q] = 0.f;

  for (int ks = 0; ks < 8; ++ks) {
    bf16x8 a[4];
#pragma unroll
    for (int mf = 0; mf < 4; ++mf) {
      int m = m0 + w * 64 + mf * 16 + rl;
      const float* xp = x + m * 256 + ks * 32 + kg * 8;
      f32x4 v0 = *(const f32x4*)xp;
      f32x4 v1 = *(const f32x4*)(xp + 4);
      bf16x8 av;
      av[0] = (__bf16)v0[0]; av[1] = (__bf16)v0[1]; av[2] = (__bf16)v0[2]; av[3] = (__bf16)v0[3];
      av[4] = (__bf16)v1[0]; av[5] = (__bf16)v1[1]; av[6] = (__bf16)v1[2]; av[7] = (__bf16)v1[3];
      a[mf] = av;
    }
#pragma unroll
    for (int nf = 0; nf < 9; ++nf) {
      bf16x8 bfr = *(const bf16x8*)(wct + (nf * 16 + rl) * 256 + ks * 32 + kg * 8);
#pragma unroll
      for (int mf = 0; mf < 4; ++mf)
        acc[mf][nf] = __builtin_amdgcn_mfma_f32_16x16x32_bf16(a[mf], bfr, acc[mf][nf], 0, 0, 0);
    }
  }

#pragma unroll
  for (int nf = 0; nf < 9; ++nf) {
    int ch = nf * 16 + rl;
    float s = sc[ch], shv = sh[ch];
#pragma unroll
    for (int mf = 0; mf < 4; ++mf) {
      int pbase = posb + w * 64 + mf * 16 + kg * 4;
      union { __bf16 h[4]; uint2 u; } pk;
#pragma unroll
      for (int r = 0; r < 4; ++r) pk.h[r] = (__bf16)(acc[mf][nf][r] * s + shv);
      if (ch < 64) {
#pragma unroll
        for (int r = 0; r < 4; ++r)
          qp[(size_t)(b * 4096 + pbase + r) * 64 + ch] = pk.h[r];
      } else if (ch < 80) {
        *(uint2*)(kt + (size_t)(b * 16 + ch - 64) * 4096 + pbase) = pk.u;
      } else {
        *(uint2*)(vt + (size_t)(b * 64 + ch - 80) * 4096 + pbase) = pk.u;
      }
    }
  }
}

// ------------------------------------------------------------------
// Kernel B1: per (b, k-channel) softmax max & 1/sum over 4096 positions
// ------------------------------------------------------------------
__global__ void kB1(char* ws) {
  __shared__ float red[256];
  int t = threadIdx.x;
  int b = blockIdx.x >> 4, kk = blockIdx.x & 15;
  const __bf16* kt = (const __bf16*)(ws + KT_OFF) + (size_t)(b * 16 + kk) * 4096;
  float v[16];
  bf16x8 c0 = *(const bf16x8*)(kt + t * 16);
  bf16x8 c1 = *(const bf16x8*)(kt + t * 16 + 8);
#pragma unroll
  for (int i = 0; i < 8; ++i) { v[i] = (float)c0[i]; v[8 + i] = (float)c1[i]; }
  float mx = v[0];
#pragma unroll
  for (int i = 1; i < 16; ++i) mx = fmaxf(mx, v[i]);
  red[t] = mx; __syncthreads();
  for (int s = 128; s > 0; s >>= 1) { if (t < s) red[t] = fmaxf(red[t], red[t + s]); __syncthreads(); }
  mx = red[0]; __syncthreads();
  float se = 0.f;
#pragma unroll
  for (int i = 0; i < 16; ++i) se += expf(v[i] - mx);
  red[t] = se; __syncthreads();
  for (int s = 128; s > 0; s >>= 1) { if (t < s) red[t] += red[t + s]; __syncthreads(); }
  if (t == 0) {
    float* ms = (float*)(ws + MSUM_OFF);
    ms[(b * 16 + kk) * 2] = mx;
    ms[(b * 16 + kk) * 2 + 1] = 1.f / red[0];
  }
}

// ------------------------------------------------------------------
// Kernel B2: LcB[b][k][v] = sum_n softmax(k)[n]*v[v][n] + pos_b[k]
// ------------------------------------------------------------------
__global__ __launch_bounds__(256) void kB2(char* ws, const float* pos_b) {
  __shared__ float red[16][256];
  int t = threadIdx.x;
  int b = blockIdx.x >> 6, v = blockIdx.x & 63;
  const __bf16* kt = (const __bf16*)(ws + KT_OFF) + (size_t)b * 16 * 4096;
  const __bf16* vt = (const __bf16*)(ws + VT_OFF) + (size_t)(b * 64 + v) * 4096;
  const float* ms = (const float*)(ws + MSUM_OFF) + b * 32;
  float mx[16];
#pragma unroll
  for (int i = 0; i < 16; ++i) mx[i] = ms[2 * i];
  float acc[16];
#pragma unroll
  for (int i = 0; i < 16; ++i) acc[i] = 0.f;
  for (int c = 0; c < 16; ++c) {
    int p = c * 256 + t;
    float vv = (float)vt[p];
#pragma unroll
    for (int i = 0; i < 16; ++i)
      acc[i] += expf((float)kt[i * 4096 + p] - mx[i]) * vv;
  }
#pragma unroll
  for (int i = 0; i < 16; ++i) red[i][t] = acc[i];
  __syncthreads();
  for (int s = 128; s > 0; s >>= 1) {
    if (t < s) {
#pragma unroll
      for (int i = 0; i < 16; ++i) red[i][t] += red[i][t + s];
    }
    __syncthreads();
  }
  if (t < 16) {
    float* lcb = (float*)(ws + LCB_OFF);
    lcb[(b * 16 + t) * 64 + v] = red[t][0] * ms[2 * t + 1] + pos_b[t];
  }
}

// ------------------------------------------------------------------
// Kernel C: 23x23 conv as banded GEMM, MFMA 32x32x16 bf16.
// Block = (b, v-pair). M=128 (2v x 64y), N=256 (16x x 16k) per x-tile, K=48/dy.
// ------------------------------------------------------------------
__global__ __launch_bounds__(256, 2) void kC(char* ws, int b0) {
  __shared__ __align__(16) u16 imgp[2 * 86 * 128];  // padded images, XOR-swizzled
  __shared__ __align__(16) u16 bbuf[12288];         // one dy's B matrix
  int t = threadIdx.x, w = t >> 6, l = t & 63;
  int bb = blockIdx.x >> 5;
  int b = b0 + bb;
  int vp = blockIdx.x & 31;
  int vbase = vp * 2;
  const __bf16* vt = (const __bf16*)(ws + VT_OFF);
  const u16* bst = (const u16*)(ws + BST_OFF);
  __bf16* lp = (__bf16*)(ws + LP_OFF) + (size_t)bb * 4194304;

  // zero the padded image buffer
  bf16x8 z;
#pragma unroll
  for (int q = 0; q < 8; ++q) z[q] = (__bf16)0.f;
#pragma unroll
  for (int i = 0; i < 11; ++i) {
    int idx = (t + i * 256) * 8;
    if (idx < 22016) *(bf16x8*)(imgp + idx) = z;
  }
  __syncthreads();
  // stage interior (zero halo: rows 11..74, logical cols 16..79), swizzled
#pragma unroll
  for (int i = 0; i < 4; ++i) {
    int slot = t + i * 256;            // < 1024 = 2v * 64y * 8chunks
    int vs = slot >> 9, s2 = slot & 511;
    int y = s2 >> 3, xc = (s2 & 7) * 8;
    bf16x8 val = *(const bf16x8*)(vt + (size_t)(b * 64 + vbase + vs) * 4096 + y * 64 + xc);
    int r = 11 + y;
    int col = (16 + xc) ^ ((r & 15) << 3);
    *(bf16x8*)(imgp + vs * 11008 + r * 128 + col) = val;
  }
  __syncthreads();

  int wm = (w >> 1) * 64, wn = (w & 1) * 128;
  for (int xt = 0; xt < 4; ++xt) {
    int x0 = xt * 16;
    f32x16 acc[2][4];
#pragma unroll
    for (int mf = 0; mf < 2; ++mf)
#pragma unroll
      for (int nf = 0; nf < 4; ++nf)
#pragma unroll
        for (int q = 0; q < 16; ++q) acc[mf][nf][q] = 0.f;

    for (int dy = 0; dy < 23; ++dy) {
      __syncthreads();                 // protect bbuf from prior readers
      const uint4* src = (const uint4*)(bst + dy * 12288);
#pragma unroll
      for (int i = 0; i < 6; ++i) {
        int idx = t + i * 256;         // < 1536
        *(uint4*)(bbuf + idx * 8) = src[idx];
      }
      __syncthreads();

      bf16x8 a[2][3];
#pragma unroll
      for (int mf = 0; mf < 2; ++mf) {
        int row = wm + mf * 32 + (l & 31);
        int vs = row >> 6, y = row & 63;
        int r = y + dy;
        const u16* base = imgp + vs * 11008 + r * 128;
#pragma unroll
        for (int ks = 0; ks < 3; ++ks) {
          int col = (x0 + ks * 16 + (l >> 5) * 8) ^ ((r & 15) << 3);
          a[mf][ks] = *(const bf16x8*)(base + col);
        }
      }
#pragma unroll
      for (int nf = 0; nf < 4; ++nf) {
        int nt = (wn >> 5) + nf;
#pragma unroll
        for (int ks = 0; ks < 3; ++ks) {
          bf16x8 bfr = *(const bf16x8*)(bbuf + ((nt * 3 + ks) * 64 + l) * 8);
          acc[0][nf] = __builtin_amdgcn_mfma_f32_32x32x16_bf16(a[0][ks], bfr, acc[0][nf], 0, 0, 0);
          acc[1][nf] = __builtin_amdgcn_mfma_f32_32x32x16_bf16(a[1][ks], bfr, acc[1][nf], 0, 0, 0);
        }
      }
    }
    // epilogue: Lp[pos][v*16+k] bf16
#pragma unroll
    for (int mf = 0; mf < 2; ++mf) {
#pragma unroll
      for (int nf = 0; nf < 4; ++nf) {
        int n = wn + nf * 32 + (l & 31);
        int x = x0 + (n >> 4), kch = n & 15;
#pragma unroll
        for (int r = 0; r < 16; ++r) {
          int row = wm + mf * 32 + (r & 3) + 8 * (r >> 2) + 4 * (l >> 5);
          int v = vbase + (row >> 6), y = row & 63;
          lp[(size_t)(y * 64 + x) * 1024 + v * 16 + kch] = (__bf16)acc[mf][nf][r];
        }
      }
    }
  }
}

// ------------------------------------------------------------------
// Kernel D: Y[b][pos][h*64+v] = sum_k q[pos][h*16+k]*(LcB[k][v] + Lp[pos][v*16+k])
// ------------------------------------------------------------------
__global__ __launch_bounds__(256) void kD(const char* ws, float* out, int b0) {
  int t = threadIdx.x;
  int h = t >> 6, v = t & 63;
  int bb = blockIdx.x >> 6, pt = blockIdx.x & 63;
  int b = b0 + bb;
  const __bf16* qp = (const __bf16*)(ws + QP_OFF) + (size_t)b * 4096 * 64;
  const __bf16* lp = (const __bf16*)(ws + LP_OFF) + (size_t)bb * 4194304;
  const float* lcb = (const float*)(ws + LCB_OFF) + b * 1024;
  float lc[16];
#pragma unroll
  for (int i = 0; i < 16; ++i) lc[i] = lcb[i * 64 + v];
  int p0 = pt * 64;
  for (int pp = 0; pp < 64; ++pp) {
    int p = p0 + pp;
    const __bf16* qrow = qp + (size_t)p * 64 + h * 16;
    const __bf16* lrow = lp + (size_t)p * 1024 + v * 16;
    bf16x8 q0 = *(const bf16x8*)qrow;
    bf16x8 q1 = *(const bf16x8*)(qrow + 8);
    bf16x8 l0 = *(const bf16x8*)lrow;
    bf16x8 l1 = *(const bf16x8*)(lrow + 8);
    float sum = 0.f;
#pragma unroll
    for (int i = 0; i < 8; ++i) {
      sum += (float)q0[i] * (lc[i] + (float)l0[i]);
      sum += (float)q1[i] * (lc[8 + i] + (float)l1[i]);
    }
    out[((size_t)b * 4096 + p) * 256 + t] = sum;
  }
}

extern "C" void kernel_launch(void* const* d_in, const int* in_sizes, int n_in,
                              void* d_out, int out_size, void* d_ws, size_t ws_size,
                              hipStream_t stream) {
  const float* x   = (const float*)d_in[0];
  const float* Wq  = (const float*)d_in[1];
  const float* Wk  = (const float*)d_in[2];
  const float* Wv  = (const float*)d_in[3];
  const float* gq  = (const float*)d_in[4];
  const float* bq  = (const float*)d_in[5];
  const float* mq  = (const float*)d_in[6];
  const float* vq  = (const float*)d_in[7];
  const float* gv  = (const float*)d_in[8];
  const float* bv  = (const float*)d_in[9];
  const float* mv  = (const float*)d_in[10];
  const float* vvr = (const float*)d_in[11];
  const float* pw  = (const float*)d_in[12];
  const float* pb  = (const float*)d_in[13];
  char* ws = (char*)d_ws;
  float* out = (float*)d_out;

  hipLaunchKernelGGL(kP, dim3(24), dim3(256), 0, stream,
                     Wq, Wk, Wv, gq, bq, mq, vq, gv, bv, mv, vvr, pw, ws);
  hipLaunchKernelGGL(kA, dim3(256), dim3(256), 0, stream, x, ws);
  hipLaunchKernelGGL(kB1, dim3(256), dim3(256), 0, stream, ws);
  hipLaunchKernelGGL(kB2, dim3(1024), dim3(256), 0, stream, ws, pb);

  size_t avail = ws_size > LP_OFF ? ws_size - LP_OFF : 0;
  int nb = (int)(avail / LP_PER_B);
  if (nb < 1) nb = 1;
  if (nb > 16) nb = 16;
  for (int b0 = 0; b0 < 16; b0 += nb) {
    int cur = (16 - b0 < nb) ? 16 - b0 : nb;
    hipLaunchKernelGGL(kC, dim3(cur * 32), dim3(256), 0, stream, ws, b0);
    hipLaunchKernelGGL(kD, dim3(cur * 64), dim3(256), 0, stream, ws, out, b0);
  }
}